// Round 2
// baseline (423.604 us; speedup 1.0000x reference)
//
#include <hip/hip_runtime.h>

#define DIM    64      // CELL_DIM
#define NCELLS 512
#define CHUNK  256     // cells per chunk (2 chunks cover 512)
#define KHALF  32      // k-values staged per phase (half of DIM)
#define ROWS_PER_BLOCK 8
#define NROWS  8192

// R3: occupancy fix. LDS halved to 32 KB (stage K in halves -> 4 phases),
// grid doubled to 1024 blocks -> 4 blocks/CU = 4 waves/SIMD (was 2).
// Block: 256 threads = 4 waves. Wave w owns rows rowBase..rowBase+1.
// Lane l owns cells {ch*256 + 4l .. 4l+3} per chunk ch.
// x broadcast reverted to wave-uniform global loads (R2's v_readlane put the
// broadcast on the VALU pipe and regressed; uniform loads ride the scalar/VMEM
// pipe and overlap).
// Accumulators are named float4s (NOT arrays) — local arrays with loop-variable
// indices land in scratch.
__global__ __launch_bounds__(256, 4)
void placecells_kernel(const float* __restrict__ x,
                       const float* __restrict__ pc,
                       float* __restrict__ out)
{
    __shared__ float pcT[KHALF * CHUNK];   // 32 KB, [k][cell] XOR-swizzled

    const int tid = (int)threadIdx.x;
    const int l   = tid & 63;
    const int w   = __builtin_amdgcn_readfirstlane(tid >> 6);
    const int rowBase = (int)blockIdx.x * ROWS_PER_BLOCK + w * 2;

    // a{row}{chunk}: 4 cells each -> 16 accumulator VGPRs
    float4 a00{0,0,0,0}, a01{0,0,0,0};
    float4 a10{0,0,0,0}, a11{0,0,0,0};

    // 4 phases: (chunk ch, k-half h). Fully unrolled so ch/h are compile-time
    // (rule: runtime-selected refs/indices spill to scratch).
    #pragma unroll
    for (int ph = 0; ph < 4; ++ph) {
        const int ch = ph >> 1;        // cell chunk: 0,0,1,1
        const int h  = ph & 1;         // k half:     0,1,0,1
        if (ph) __syncthreads();       // pcT reuse: prev compute must finish

        // ---- stage: global pc[cell][k-half] -> LDS pcT[k][cell], swizzled ----
        // 256 cells x 32 k = 2048 float4s over 256 threads = 8 iters.
        // Wave-level: lanes cover 8 consecutive cells x 8 k-quads -> contiguous
        // 128B per cell row, coalesced.
        #pragma unroll
        for (int it = 0; it < 8; ++it) {
            int idx = it * 256 + tid;          // 0..2047
            int cl  = idx >> 3;                // cell within chunk, 0..255
            int kq  = idx & 7;                 // local k-quad, 0..7
            float4 v = *(const float4*)(pc + (ch * CHUNK + cl) * DIM + h * KHALF + kq * 4);
            int k4g = h * 8 + kq;              // global k-quad, 0..15 (swizzle key)
            int pq  = (cl >> 2) ^ k4g;         // bank swizzle (matches read side)
            float* p = &pcT[(kq * 4) * CHUNK + pq * 4 + (cl & 3)];
            p[0 * CHUNK] = v.x;
            p[1 * CHUNK] = v.y;
            p[2 * CHUNK] = v.z;
            p[3 * CHUNK] = v.w;
        }
        __syncthreads();

        float4& A0 = (ch == 0) ? a00 : a01;    // compile-time after unroll
        float4& A1 = (ch == 0) ? a10 : a11;

        // ---- K loop: 2 rows x 4 cells x 4 k per iteration ----
        #pragma unroll
        for (int kq = 0; kq < 8; ++kq) {
            const int k4g = h * 8 + kq;
            // wave-uniform addresses -> scalarized by compiler (s_load), L1-hot
            float4 xv0 = *(const float4*)(x + (rowBase + 0) * DIM + h * KHALF + kq * 4);
            float4 xv1 = *(const float4*)(x + (rowBase + 1) * DIM + h * KHALF + kq * 4);
            const int pq4 = (l ^ k4g) * 4;     // undo swizzle: logical quad = l
            #pragma unroll
            for (int j = 0; j < 4; ++j) {
                float4 pv = *(const float4*)(&pcT[(kq * 4 + j) * CHUNK + pq4]);
                float x0 = (j == 0) ? xv0.x : (j == 1) ? xv0.y : (j == 2) ? xv0.z : xv0.w;
                float x1 = (j == 0) ? xv1.x : (j == 1) ? xv1.y : (j == 2) ? xv1.z : xv1.w;
                A0.x += fabsf(x0 - pv.x); A0.y += fabsf(x0 - pv.y);
                A0.z += fabsf(x0 - pv.z); A0.w += fabsf(x0 - pv.w);
                A1.x += fabsf(x1 - pv.x); A1.y += fabsf(x1 - pv.y);
                A1.z += fabsf(x1 - pv.z); A1.w += fabsf(x1 - pv.w);
            }
        }
    }

    // ---- softmax per row over 512 cells (one wave holds a whole row) ----
    auto finish_row = [&](float4 a, float4 b, int r) {
        // min L1 == min d^2 (d >= 0) -> exact max-subtraction
        float mn = fminf(fminf(fminf(a.x, a.y), fminf(a.z, a.w)),
                         fminf(fminf(b.x, b.y), fminf(b.z, b.w)));
        #pragma unroll
        for (int off = 32; off > 0; off >>= 1)
            mn = fminf(mn, __shfl_xor(mn, off, 64));
        float m2 = mn * mn;

        float e0 = __expf(0.5f * (m2 - a.x * a.x));
        float e1 = __expf(0.5f * (m2 - a.y * a.y));
        float e2 = __expf(0.5f * (m2 - a.z * a.z));
        float e3 = __expf(0.5f * (m2 - a.w * a.w));
        float e4 = __expf(0.5f * (m2 - b.x * b.x));
        float e5 = __expf(0.5f * (m2 - b.y * b.y));
        float e6 = __expf(0.5f * (m2 - b.z * b.z));
        float e7 = __expf(0.5f * (m2 - b.w * b.w));
        float s = ((e0 + e1) + (e2 + e3)) + ((e4 + e5) + (e6 + e7));
        #pragma unroll
        for (int off = 32; off > 0; off >>= 1)
            s += __shfl_xor(s, off, 64);
        float inv = 1.0f / s;

        float* orow = out + (size_t)(rowBase + r) * NCELLS;
        *(float4*)(orow + 4 * l)         = make_float4(e0 * inv, e1 * inv, e2 * inv, e3 * inv);
        *(float4*)(orow + CHUNK + 4 * l) = make_float4(e4 * inv, e5 * inv, e6 * inv, e7 * inv);
    };
    finish_row(a00, a01, 0);
    finish_row(a10, a11, 1);
}

extern "C" void kernel_launch(void* const* d_in, const int* in_sizes, int n_in,
                              void* d_out, int out_size, void* d_ws, size_t ws_size,
                              hipStream_t stream)
{
    const float* x  = (const float*)d_in[0];   // (8192, 64) fp32
    const float* pc = (const float*)d_in[1];   // (512, 64) fp32
    float* out = (float*)d_out;                // (8192, 512) fp32
    placecells_kernel<<<dim3(NROWS / ROWS_PER_BLOCK), dim3(256), 0, stream>>>(x, pc, out);
}

// Round 3
// 80.367 us; speedup vs baseline: 5.2708x; 5.2708x over previous
//
#include <hip/hip_runtime.h>

#define DIM    64      // CELL_DIM
#define NCELLS 512
#define CHUNK  256     // cells per chunk (2 chunks cover 512)
#define KHALF  32      // k-values staged per phase (half of DIM)
#define ROWS_PER_BLOCK 8
#define NROWS  8192

// R3: occupancy fix, done register-safe this time.
// 32 KB LDS (stage K in halves -> 4 phases), grid 1024 blocks ->
// 5 blocks/CU = 5 waves/SIMD (R0/R1 had 2 with 64 KB LDS).
// R2 POST-MORTEM: `float4& A0 = cond ? a00 : a01` (runtime-selected
// reference) pushed accumulators to scratch -> 1.1 GB HBM spill traffic,
// 376 us. Accumulators MUST be named float4s passed as reference
// PARAMETERS at distinct call sites with compile-time phase constants —
// the R0/R1 pattern that provably stays in VGPRs.
__global__ __launch_bounds__(256, 4)
void placecells_kernel(const float* __restrict__ x,
                       const float* __restrict__ pc,
                       float* __restrict__ out)
{
    __shared__ float pcT[KHALF * CHUNK];   // 32 KB, [k][cell] XOR-swizzled

    const int tid = (int)threadIdx.x;
    const int l   = tid & 63;
    const int w   = __builtin_amdgcn_readfirstlane(tid >> 6);
    const int rowBase = (int)blockIdx.x * ROWS_PER_BLOCK + w * 2;

    // a{row}{chunk}: 4 cells each -> 16 accumulator VGPRs
    float4 a00{0,0,0,0}, a01{0,0,0,0};
    float4 a10{0,0,0,0}, a11{0,0,0,0};

    // One phase = stage 256 cells x 32 k into LDS, then accumulate.
    // ch, h are compile-time at every call site; A0/A1 bind to distinct
    // named float4s per call site (register-resident, R0/R1-proven).
    auto do_phase = [&](int ch, int h, float4& A0, float4& A1) {
        // ---- stage: global pc[cell][k-half] -> LDS pcT[k][cell], swizzled ----
        // 256 cells x 32 k = 2048 float4s over 256 threads = 8 iters.
        #pragma unroll
        for (int it = 0; it < 8; ++it) {
            int idx = it * 256 + tid;          // 0..2047
            int cl  = idx >> 3;                // cell within chunk, 0..255
            int kq  = idx & 7;                 // local k-quad, 0..7
            float4 v = *(const float4*)(pc + (ch * CHUNK + cl) * DIM + h * KHALF + kq * 4);
            int k4g = h * 8 + kq;              // global k-quad (swizzle key)
            int pq  = (cl >> 2) ^ k4g;         // bank swizzle (matches read side)
            float* p = &pcT[(kq * 4) * CHUNK + pq * 4 + (cl & 3)];
            p[0 * CHUNK] = v.x;
            p[1 * CHUNK] = v.y;
            p[2 * CHUNK] = v.z;
            p[3 * CHUNK] = v.w;
        }
        __syncthreads();

        // ---- K loop: 2 rows x 4 cells x 4 k per iteration ----
        #pragma unroll
        for (int kq = 0; kq < 8; ++kq) {
            const int k4g = h * 8 + kq;
            // wave-uniform addresses -> scalarizable (rowBase from readfirstlane)
            float4 xv0 = *(const float4*)(x + (rowBase + 0) * DIM + h * KHALF + kq * 4);
            float4 xv1 = *(const float4*)(x + (rowBase + 1) * DIM + h * KHALF + kq * 4);
            const int pq4 = (l ^ k4g) * 4;     // undo swizzle: logical quad = l
            #pragma unroll
            for (int j = 0; j < 4; ++j) {
                float4 pv = *(const float4*)(&pcT[(kq * 4 + j) * CHUNK + pq4]);
                float x0 = (j == 0) ? xv0.x : (j == 1) ? xv0.y : (j == 2) ? xv0.z : xv0.w;
                float x1 = (j == 0) ? xv1.x : (j == 1) ? xv1.y : (j == 2) ? xv1.z : xv1.w;
                A0.x += fabsf(x0 - pv.x); A0.y += fabsf(x0 - pv.y);
                A0.z += fabsf(x0 - pv.z); A0.w += fabsf(x0 - pv.w);
                A1.x += fabsf(x1 - pv.x); A1.y += fabsf(x1 - pv.y);
                A1.z += fabsf(x1 - pv.z); A1.w += fabsf(x1 - pv.w);
            }
        }
        __syncthreads();   // pcT reused by next phase
    };

    do_phase(0, 0, a00, a10);
    do_phase(0, 1, a00, a10);
    do_phase(1, 0, a01, a11);
    do_phase(1, 1, a01, a11);

    // ---- softmax per row over 512 cells (one wave holds a whole row) ----
    auto finish_row = [&](float4 a, float4 b, int r) {
        // min L1 == min d^2 (d >= 0) -> exact max-subtraction
        float mn = fminf(fminf(fminf(a.x, a.y), fminf(a.z, a.w)),
                         fminf(fminf(b.x, b.y), fminf(b.z, b.w)));
        #pragma unroll
        for (int off = 32; off > 0; off >>= 1)
            mn = fminf(mn, __shfl_xor(mn, off, 64));
        float m2 = mn * mn;

        float e0 = __expf(0.5f * (m2 - a.x * a.x));
        float e1 = __expf(0.5f * (m2 - a.y * a.y));
        float e2 = __expf(0.5f * (m2 - a.z * a.z));
        float e3 = __expf(0.5f * (m2 - a.w * a.w));
        float e4 = __expf(0.5f * (m2 - b.x * b.x));
        float e5 = __expf(0.5f * (m2 - b.y * b.y));
        float e6 = __expf(0.5f * (m2 - b.z * b.z));
        float e7 = __expf(0.5f * (m2 - b.w * b.w));
        float s = ((e0 + e1) + (e2 + e3)) + ((e4 + e5) + (e6 + e7));
        #pragma unroll
        for (int off = 32; off > 0; off >>= 1)
            s += __shfl_xor(s, off, 64);
        float inv = 1.0f / s;

        float* orow = out + (size_t)(rowBase + r) * NCELLS;
        *(float4*)(orow + 4 * l)         = make_float4(e0 * inv, e1 * inv, e2 * inv, e3 * inv);
        *(float4*)(orow + CHUNK + 4 * l) = make_float4(e4 * inv, e5 * inv, e6 * inv, e7 * inv);
    };
    finish_row(a00, a01, 0);
    finish_row(a10, a11, 1);
}

extern "C" void kernel_launch(void* const* d_in, const int* in_sizes, int n_in,
                              void* d_out, int out_size, void* d_ws, size_t ws_size,
                              hipStream_t stream)
{
    const float* x  = (const float*)d_in[0];   // (8192, 64) fp32
    const float* pc = (const float*)d_in[1];   // (512, 64) fp32
    float* out = (float*)d_out;                // (8192, 512) fp32
    placecells_kernel<<<dim3(NROWS / ROWS_PER_BLOCK), dim3(256), 0, stream>>>(x, pc, out);
}

// Round 4
// 79.042 us; speedup vs baseline: 5.3592x; 1.0168x over previous
//
#include <hip/hip_runtime.h>

#define DIM    64      // CELL_DIM
#define NCELLS 512
#define ROWS_PER_BLOCK 32
#define NROWS  8192
#define NBLOCKS (NROWS / ROWS_PER_BLOCK)   // 256 = one block per CU

// R4: kill the phase machinery. pc is 128 KB and fits in LDS whole (160 KB/CU).
// Evidence: R0 (2 phases, 2 blk/CU) == R3 (4 phases, 5 blk/CU) == ~39 us kernel
// -> occupancy and x-loads are NOT the bottleneck; the repeated
// stage->barrier->compute->barrier structure is. This version stages pc ONCE
// (one barrier total) and runs a single uninterrupted K loop.
// Block: 1024 threads = 16 waves, 1 block/CU (LDS-bound), 4 waves/SIMD.
// Wave w owns rows rowBase..rowBase+1; lane l owns cells {4l..4l+3} (chunk A)
// and {256+4l..+3} (chunk B).
// Accumulators are named float4s (R2 lesson: no runtime-selected refs/indices).
__global__ __launch_bounds__(1024, 4)
void placecells_kernel(const float* __restrict__ x,
                       const float* __restrict__ pc,
                       float* __restrict__ out)
{
    extern __shared__ float pcT[];   // [64 k][512 cells] = 128 KB, quad-swizzled

    const int tid = (int)threadIdx.x;
    const int l   = tid & 63;
    const int w   = __builtin_amdgcn_readfirstlane(tid >> 6);
    const int rowBase = (int)blockIdx.x * ROWS_PER_BLOCK + w * 2;

    // ---- stage ALL of pc once: global [cell][k] -> LDS pcT[k][cell] ----
    // 512 cells x 16 k-quads = 8192 float4s over 1024 threads = 8 iters.
    // Global: 16 consecutive lanes cover one cell's 256 B -> 1 KB/wave, coalesced.
    // LDS write banks: (pq*4 + cl&3) mod 32 -> 32 banks x 2 lanes = free 2-way.
    #pragma unroll
    for (int it = 0; it < 8; ++it) {
        int idx = it * 1024 + tid;        // 0..8191
        int cl  = idx >> 4;               // cell, 0..511
        int kq  = idx & 15;               // k-quad, 0..15
        float4 v = *(const float4*)(pc + cl * DIM + kq * 4);
        int pq = (cl >> 2) ^ kq;          // swizzle 16B quads within each k-row
        float* p = &pcT[(kq * 4) * NCELLS + pq * 4 + (cl & 3)];
        p[0 * NCELLS] = v.x;
        p[1 * NCELLS] = v.y;
        p[2 * NCELLS] = v.z;
        p[3 * NCELLS] = v.w;
    }
    __syncthreads();   // the ONLY barrier in the kernel

    // a{row}{chunk}: 16 accumulator VGPRs
    float4 a0A{0,0,0,0}, a0B{0,0,0,0};
    float4 a1A{0,0,0,0}, a1B{0,0,0,0};

    // ---- K loop: per k, 2 conflict-free ds_read_b128 feed 32 VALU accums ----
    #pragma unroll 4
    for (int k4 = 0; k4 < 16; ++k4) {
        // wave-uniform x addresses (L2-hot, off the critical path per R1)
        float4 xv0 = *(const float4*)(x + (rowBase + 0) * DIM + k4 * 4);
        float4 xv1 = *(const float4*)(x + (rowBase + 1) * DIM + k4 * 4);
        const int pqA = (l ^ k4) * 4;     // undo swizzle: logical quad = l
        #pragma unroll
        for (int j = 0; j < 4; ++j) {
            const float* rowp = &pcT[(k4 * 4 + j) * NCELLS];
            float4 pvA = *(const float4*)(rowp + pqA);        // cells 4l..4l+3
            float4 pvB = *(const float4*)(rowp + pqA + 256);  // cells 256+4l..+3
            float x0 = (j == 0) ? xv0.x : (j == 1) ? xv0.y : (j == 2) ? xv0.z : xv0.w;
            float x1 = (j == 0) ? xv1.x : (j == 1) ? xv1.y : (j == 2) ? xv1.z : xv1.w;
            a0A.x += fabsf(x0 - pvA.x); a0A.y += fabsf(x0 - pvA.y);
            a0A.z += fabsf(x0 - pvA.z); a0A.w += fabsf(x0 - pvA.w);
            a0B.x += fabsf(x0 - pvB.x); a0B.y += fabsf(x0 - pvB.y);
            a0B.z += fabsf(x0 - pvB.z); a0B.w += fabsf(x0 - pvB.w);
            a1A.x += fabsf(x1 - pvA.x); a1A.y += fabsf(x1 - pvA.y);
            a1A.z += fabsf(x1 - pvA.z); a1A.w += fabsf(x1 - pvA.w);
            a1B.x += fabsf(x1 - pvB.x); a1B.y += fabsf(x1 - pvB.y);
            a1B.z += fabsf(x1 - pvB.z); a1B.w += fabsf(x1 - pvB.w);
        }
    }

    // ---- softmax per row over 512 cells (one wave holds a whole row) ----
    auto finish_row = [&](float4 a, float4 b, int r) {
        // min L1 == min d^2 (d >= 0) -> exact max-subtraction
        float mn = fminf(fminf(fminf(a.x, a.y), fminf(a.z, a.w)),
                         fminf(fminf(b.x, b.y), fminf(b.z, b.w)));
        #pragma unroll
        for (int off = 32; off > 0; off >>= 1)
            mn = fminf(mn, __shfl_xor(mn, off, 64));
        float m2 = mn * mn;

        float e0 = __expf(0.5f * (m2 - a.x * a.x));
        float e1 = __expf(0.5f * (m2 - a.y * a.y));
        float e2 = __expf(0.5f * (m2 - a.z * a.z));
        float e3 = __expf(0.5f * (m2 - a.w * a.w));
        float e4 = __expf(0.5f * (m2 - b.x * b.x));
        float e5 = __expf(0.5f * (m2 - b.y * b.y));
        float e6 = __expf(0.5f * (m2 - b.z * b.z));
        float e7 = __expf(0.5f * (m2 - b.w * b.w));
        float s = ((e0 + e1) + (e2 + e3)) + ((e4 + e5) + (e6 + e7));
        #pragma unroll
        for (int off = 32; off > 0; off >>= 1)
            s += __shfl_xor(s, off, 64);
        float inv = 1.0f / s;

        float* orow = out + (size_t)(rowBase + r) * NCELLS;
        *(float4*)(orow + 4 * l)       = make_float4(e0 * inv, e1 * inv, e2 * inv, e3 * inv);
        *(float4*)(orow + 256 + 4 * l) = make_float4(e4 * inv, e5 * inv, e6 * inv, e7 * inv);
    };
    finish_row(a0A, a0B, 0);
    finish_row(a1A, a1B, 1);
}

extern "C" void kernel_launch(void* const* d_in, const int* in_sizes, int n_in,
                              void* d_out, int out_size, void* d_ws, size_t ws_size,
                              hipStream_t stream)
{
    const float* x  = (const float*)d_in[0];   // (8192, 64) fp32
    const float* pc = (const float*)d_in[1];   // (512, 64) fp32
    float* out = (float*)d_out;                // (8192, 512) fp32
    placecells_kernel<<<dim3(NBLOCKS), dim3(1024), DIM * NCELLS * sizeof(float), stream>>>(x, pc, out);
}